// Round 1
// 278.308 us; speedup vs baseline: 1.3263x; 1.3263x over previous
//
#include <hip/hip_runtime.h>
#include <hip/hip_bf16.h>
#include <math.h>

#define L2E 1.4426950408889634f
#define T_STEPS 8192
#define KTOT 5104   // 8 channels * 638 spatial (22*29)
#define EPS_LTC 1e-8f
#define KP 5120     // permuted/padded K (160 chunks x 32)

// scan chunking: 1024 chunks x 8 steps, 16-step burn-in (chunks 0,1 exact).
#define SCAN_CHUNKS 1024
#define S_PER  8
#define WARM   16

// ws layout (floats): base 315,584 f = 1,262,336 B; optional pre-split B adds
// 2 x 327,680 ushorts = 1,310,720 B  ->  total 2,573,056 B (gated on ws_size).
#define WS_BASE_FLOATS 315584
#define WS_NEED_BSP    2573056

typedef __attribute__((ext_vector_type(8))) short bfrag;   // 8 bf16 (4 VGPR)
typedef __attribute__((ext_vector_type(4))) float ffrag;   // 4 fp32 acc
typedef __attribute__((ext_vector_type(4))) float fvec4;

__device__ __forceinline__ float softplus_f(float x) {
    return log1pf(expf(-fabsf(x))) + fmaxf(x, 0.f);
}

__device__ __forceinline__ unsigned short bf_hi(float f) {  // RNE fp32->bf16
    unsigned u = __float_as_uint(f);
    u = u + 0x7FFFu + ((u >> 16) & 1u);
    return (unsigned short)(u >> 16);
}

__device__ __forceinline__ float elu_f(float x) {
    return (x > 0.f) ? x : (__builtin_amdgcn_exp2f(x * L2E) - 1.f);
}

// ---------------------------------------------------------------------------
// K0: parameter precompute (tiny).
// ---------------------------------------------------------------------------
__global__ void k0_precompute(
    const float* __restrict__ sw, const float* __restrict__ smu,
    const float* __restrict__ ssig, const float* __restrict__ serev,
    const float* __restrict__ smask,
    const float* __restrict__ w, const float* __restrict__ mu,
    const float* __restrict__ sigma, const float* __restrict__ erev,
    const float* __restrict__ mask,
    const float* __restrict__ gleak, const float* __restrict__ vleak,
    const float* __restrict__ cm,
    float* __restrict__ sc1, float* __restrict__ sc0,
    float* __restrict__ swe, float* __restrict__ swp,
    float* __restrict__ rc1, float* __restrict__ rc0,
    float* __restrict__ rwe, float* __restrict__ rwp,
    float* __restrict__ neu)
{
    int t = threadIdx.x;
    if (t < 608) {   // sensory (32 x 19)
        float sp = softplus_f(sw[t]);
        float c1 = ssig[t] * L2E;
        sc1[t] = c1;
        sc0[t] = c1 * smu[t];
        swe[t] = sp * serev[t];
        swp[t] = sp * smask[t];
    }
    if (t < 361) {   // recurrent (19 x 19), layout [src*19 + tgt]
        float wp = softplus_f(w[t]) * mask[t];
        float c1 = sigma[t] * L2E;
        rc1[t] = c1;
        rc0[t] = c1 * mu[t];
        rwe[t] = wp * erev[t];
        rwp[t] = wp;
    }
    if (t < 64) {
        if (t < 19) {
            float g   = softplus_f(gleak[t]);
            float cmt = softplus_f(cm[t]) * 6.f;   // ODE_UNFOLDS
            neu[t]       = cmt;
            neu[64 + t]  = g * vleak[t];
            neu[128 + t] = cmt + g + EPS_LTC;
        } else {
            neu[t] = 0.f; neu[64 + t] = 0.f; neu[128 + t] = 1.f;
        }
    }
}

// ---------------------------------------------------------------------------
// K0B v2: pre-split fc1_w into bf16 hi/lo, FRAGMENT-INTERLEAVED:
// g = (((kc*16 + q*4 + nt)*16) + mn)*8 + j ; n = nt*16+mn ; o = 2q + (j>>2) ;
// r = kc*4 + (j&3). A wave's per-(kc) B-read is 8 KB contiguous.
// ---------------------------------------------------------------------------
__global__ __launch_bounds__(256) void k0b_splitB(
    const float* __restrict__ fc1_w,
    unsigned short* __restrict__ bhi, unsigned short* __restrict__ blo)
{
    int g = blockIdx.x * 256 + threadIdx.x;   // 0 .. 64*KP-1
    int j  = g & 7;
    int mn = (g >> 3) & 15;
    int nt = (g >> 7) & 3;
    int q  = (g >> 9) & 3;
    int kc = g >> 11;
    int n  = nt * 16 + mn;
    int o  = 2 * q + (j >> 2);
    int r  = kc * 4 + (j & 3);
    float v = (r < 638) ? fc1_w[n * KTOT + o * 638 + r] : 0.f;
    unsigned short h = bf_hi(v);
    bhi[g] = h;
    blo[g] = bf_hi(v - __uint_as_float((unsigned)h << 16));
}

// ---------------------------------------------------------------------------
// K12 v11: LDS-resident x tile.
//  v10 counters: MfmaUtil 4%, VALUBusy 20%, HBM 36%, FETCH 434 MB vs ~70 MB
//  compulsory -> fetch-latency bound on x line re-fetches (16 distinct
//  samples/lane-group, lines evicted between kk iterations; L1 32 KB, per-XCD
//  live window > 4 MB L2).
//  Fix: stage the block's 16 samples (16 x 2070 f = 132.5 KB) in LDS with ONE
//  coalesced linear copy (samples are contiguous in global), then run the
//  identical conv+MFMA loop reading x from LDS. x HBM traffic -> compulsory
//  68 MB, loop's only global stream is the depth-1-prefetched B (L2-resident).
//  LDS-limited to 1 block/CU (8 waves = 2/SIMD) — acceptable: loop latency is
//  now LDS-class, not HBM-class. Epilogue buffers (47 KB) alias the x tile
//  (barrier-separated). Bank math: sample stride 2070 % 32 = 22 -> 16 distinct
//  samples spread 2-way over even banks (free, m136); q-lanes broadcast.
// ---------------------------------------------------------------------------
__global__ __launch_bounds__(512, 2) void k12_frontend(
    const float* __restrict__ x, const float* __restrict__ conv_w,
    const float* __restrict__ conv_b,
    const float* __restrict__ fc1_w, const float* __restrict__ fc1_b,
    const float* __restrict__ fc2_w, const float* __restrict__ fc2_b,
    const float* __restrict__ iw, const float* __restrict__ ib,
    const float* __restrict__ sc1, const float* __restrict__ sc0,
    const float* __restrict__ swe, const float* __restrict__ swp,
    const unsigned short* __restrict__ bhi,
    const unsigned short* __restrict__ blo, int use_bsp,
    float* __restrict__ wn_s, float* __restrict__ wd_s)
{
    // x tile: 16 samples x 2070 f = 33120 f = 132,480 B (fits 160 KB LDS).
    // After the K-loop (barrier), the same memory is reused as the epilogue
    // buffers (11,920 f needed <= 33,120 f available).
    __shared__ __align__(16) float smem[33120];
    float* redS = smem;            // [8][16][64] = 8192 f partial-C buffer
    float* hS   = smem + 8192;     // 16 x 68 = 1088 f
    float* w2S  = smem + 9312;     // [s][n] stride 65, 2080 f
    float* seqS = smem + 11392;    // [sample][s] stride 33, 528 f

    const int t    = threadIdx.x;   // 0..511
    const int b0   = blockIdx.x * 16;
    const int lane = t & 63;
    const int wv   = t >> 6;        // wave 0..7 -> K eighth
    const int q    = lane >> 4;     // quad -> channel pair 2q,2q+1
    const int mn   = lane & 15;     // sample (A) / out-within-tile (B)
    const int o0   = 2 * q;

    // ---- stage x tile: 8280 float4, perfectly coalesced linear copy ----
    {
        const float* xg = x + (size_t)b0 * 2070;
        #pragma unroll
        for (int i = 0; i < 16; i++) {
            int idx = i * 512 + t;
            fvec4 v;
            __builtin_memcpy(&v, xg + (size_t)idx * 4, 16);
            __builtin_memcpy(smem + (size_t)idx * 4, &v, 16);
        }
        if (t < 88) {               // tail: 8280 - 8192
            int idx = 8192 + t;
            fvec4 v;
            __builtin_memcpy(&v, xg + (size_t)idx * 4, 16);
            __builtin_memcpy(smem + (size_t)idx * 4, &v, 16);
        }
    }
    __syncthreads();

    // conv weights + bias for this lane's channel pair, in registers
    float cw0[12], cw1[12];
    #pragma unroll
    for (int i = 0; i < 12; i++) {
        cw0[i] = conv_w[o0 * 12 + i];
        cw1[i] = conv_w[o0 * 12 + 12 + i];
    }
    const float cb0 = conv_b[o0], cb1 = conv_b[o0 + 1];
    const float* xls = smem + mn * 2070;   // this lane's sample, in LDS

    ffrag acc[4];
    #pragma unroll
    for (int nt = 0; nt < 4; nt++) acc[nt] = (ffrag){0.f, 0.f, 0.f, 0.f};

    const int kc0 = wv * 20;

    // conv+ELU -> split-bf16 A fragments for chunk kc (x read from LDS)
    auto convA = [&](int kc, bfrag& a_hi, bfrag& a_lo) {
        float y0[4], y1[4];
        int r0  = kc * 4;
        int oh0 = (r0 * 565) >> 14;          // == r0/29 for r0 <= 637
        int ow0 = r0 - oh0 * 29;
        if (ow0 <= 25 && r0 + 3 <= 637) {
            // fast path: all 4 positions in conv row oh0; shared 2x5 window
            float xr[3][2][5];
            #pragma unroll
            for (int cc = 0; cc < 3; cc++) {
                const float* a0 = xls + cc * 690 + oh0 * 30 + ow0;
                fvec4 v0, v1;
                __builtin_memcpy(&v0, a0, 16);
                __builtin_memcpy(&v1, a0 + 30, 16);
                xr[cc][0][0] = v0.x; xr[cc][0][1] = v0.y;
                xr[cc][0][2] = v0.z; xr[cc][0][3] = v0.w;
                xr[cc][0][4] = a0[4];
                xr[cc][1][0] = v1.x; xr[cc][1][1] = v1.y;
                xr[cc][1][2] = v1.z; xr[cc][1][3] = v1.w;
                xr[cc][1][4] = a0[34];
            }
            #pragma unroll
            for (int rr = 0; rr < 4; rr++) {
                float a0v = cb0, a1v = cb1;
                #pragma unroll
                for (int cc = 0; cc < 3; cc++) {
                    float x00 = xr[cc][0][rr], x01 = xr[cc][0][rr + 1];
                    float x10 = xr[cc][1][rr], x11 = xr[cc][1][rr + 1];
                    a0v = fmaf(x00, cw0[cc * 4 + 0], a0v);
                    a0v = fmaf(x01, cw0[cc * 4 + 1], a0v);
                    a0v = fmaf(x10, cw0[cc * 4 + 2], a0v);
                    a0v = fmaf(x11, cw0[cc * 4 + 3], a0v);
                    a1v = fmaf(x00, cw1[cc * 4 + 0], a1v);
                    a1v = fmaf(x01, cw1[cc * 4 + 1], a1v);
                    a1v = fmaf(x10, cw1[cc * 4 + 2], a1v);
                    a1v = fmaf(x11, cw1[cc * 4 + 3], a1v);
                }
                y0[rr] = elu_f(a0v);
                y1[rr] = elu_f(a1v);
            }
        } else {
            // slow path (row-crossing or K tail): per-position LDS loads
            #pragma unroll
            for (int rr = 0; rr < 4; rr++) {
                int r = r0 + rr;
                if (r < 638) {
                    int oh = (r * 565) >> 14;
                    const float* xp = xls + oh * 30 + (r - oh * 29);
                    float a0v = cb0, a1v = cb1;
                    #pragma unroll
                    for (int cc = 0; cc < 3; cc++) {
                        float x00 = xp[cc * 690],      x01 = xp[cc * 690 + 1];
                        float x10 = xp[cc * 690 + 30], x11 = xp[cc * 690 + 31];
                        a0v = fmaf(x00, cw0[cc * 4 + 0], a0v);
                        a0v = fmaf(x01, cw0[cc * 4 + 1], a0v);
                        a0v = fmaf(x10, cw0[cc * 4 + 2], a0v);
                        a0v = fmaf(x11, cw0[cc * 4 + 3], a0v);
                        a1v = fmaf(x00, cw1[cc * 4 + 0], a1v);
                        a1v = fmaf(x01, cw1[cc * 4 + 1], a1v);
                        a1v = fmaf(x10, cw1[cc * 4 + 2], a1v);
                        a1v = fmaf(x11, cw1[cc * 4 + 3], a1v);
                    }
                    y0[rr] = elu_f(a0v);
                    y1[rr] = elu_f(a1v);
                } else { y0[rr] = 0.f; y1[rr] = 0.f; }
            }
        }
        #pragma unroll
        for (int j = 0; j < 4; j++) {
            unsigned short h0 = bf_hi(y0[j]);
            a_hi[j] = (short)h0;
            a_lo[j] = (short)bf_hi(y0[j] - __uint_as_float((unsigned)h0 << 16));
            unsigned short h1 = bf_hi(y1[j]);
            a_hi[4 + j] = (short)h1;
            a_lo[4 + j] = (short)bf_hi(y1[j] - __uint_as_float((unsigned)h1 << 16));
        }
    };

    if (use_bsp) {
        auto loadB = [&](int kc, bfrag* bh, bfrag* bl) {
            #pragma unroll
            for (int nt = 0; nt < 4; nt++) {
                size_t off = ((size_t)(kc * 16 + q * 4 + nt) * 16 + mn) * 8;
                bh[nt] = *(const bfrag*)(bhi + off);
                bl[nt] = *(const bfrag*)(blo + off);
            }
        };
        bfrag b_h[4], b_l[4], nb_h[4], nb_l[4];
        loadB(kc0, b_h, b_l);
        for (int kk = 0; kk < 20; kk++) {
            const int kc = kc0 + kk;
            bfrag a_hi, a_lo;
            convA(kc, a_hi, a_lo);
            if (kk < 19) loadB(kc + 1, nb_h, nb_l);   // prefetch before MFMAs
            #pragma unroll
            for (int nt = 0; nt < 4; nt++) {
                acc[nt] = __builtin_amdgcn_mfma_f32_16x16x32_bf16(a_hi, b_h[nt], acc[nt], 0, 0, 0);
                acc[nt] = __builtin_amdgcn_mfma_f32_16x16x32_bf16(a_hi, b_l[nt], acc[nt], 0, 0, 0);
                acc[nt] = __builtin_amdgcn_mfma_f32_16x16x32_bf16(a_lo, b_h[nt], acc[nt], 0, 0, 0);
            }
            #pragma unroll
            for (int nt = 0; nt < 4; nt++) { b_h[nt] = nb_h[nt]; b_l[nt] = nb_l[nt]; }
        }
    } else {
        // fallback: in-loop fp32 load + split (ws too small for pre-split B)
        for (int kk = 0; kk < 20; kk++) {
            const int kc = kc0 + kk;
            bfrag a_hi, a_lo;
            convA(kc, a_hi, a_lo);
            #pragma unroll
            for (int nt = 0; nt < 4; nt++) {
                int n = nt * 16 + mn;
                bfrag b_h, b_l;
                #pragma unroll
                for (int j = 0; j < 8; j++) {
                    int o = o0 + (j >> 2);
                    int r = kc * 4 + (j & 3);
                    float vv = (r < 638) ? fc1_w[(size_t)n * KTOT + o * 638 + r] : 0.f;
                    unsigned short h = bf_hi(vv);
                    b_h[j] = (short)h;
                    b_l[j] = (short)bf_hi(vv - __uint_as_float((unsigned)h << 16));
                }
                acc[nt] = __builtin_amdgcn_mfma_f32_16x16x32_bf16(a_hi, b_h, acc[nt], 0, 0, 0);
                acc[nt] = __builtin_amdgcn_mfma_f32_16x16x32_bf16(a_hi, b_l, acc[nt], 0, 0, 0);
                acc[nt] = __builtin_amdgcn_mfma_f32_16x16x32_bf16(a_lo, b_h, acc[nt], 0, 0, 0);
            }
        }
    }

    // all waves must be done READING the x tile before we overwrite it with
    // the epilogue buffers (smem aliasing).
    __syncthreads();

    // ---- cross-wave K reduction: 8 partials -> LDS -> sum + bias + ReLU ----
    // C/D layout: col = lane&15 -> n-within-tile, row = q*4 + reg -> m.
    #pragma unroll
    for (int nt = 0; nt < 4; nt++) {
        int n = nt * 16 + mn;
        #pragma unroll
        for (int rg = 0; rg < 4; rg++) {
            int m = q * 4 + rg;
            redS[(wv * 16 + m) * 64 + n] = acc[nt][rg];
        }
    }
    __syncthreads();
    #pragma unroll
    for (int e = 0; e < 2; e++) {
        int flat = e * 512 + t;           // 1024 = 16*64
        int m = flat >> 6, n = flat & 63;
        float s = 0.f;
        #pragma unroll
        for (int p = 0; p < 8; p++) s += redS[(p * 16 + m) * 64 + n];
        hS[m * 68 + n] = fmaxf(s + fc1_b[n], 0.f);
    }
    // ---- stage fc2 weights ----
    #pragma unroll
    for (int e = 0; e < 4; e++) {
        int flat = e * 512 + t;           // 2048 = 32*64
        int s = flat >> 6, n = flat & 63;
        w2S[s * 65 + n] = fc2_w[flat];
    }
    __syncthreads();

    // ---- fc2 + input affine -> seq (16 samples x 32 sensory = 512 items) ----
    {
        int s = t & 31, bl = t >> 5;
        float a2 = fc2_b[s];
        #pragma unroll 8
        for (int n = 0; n < 64; n++)
            a2 = fmaf(hS[bl * 68 + n], w2S[s * 65 + n], a2);
        seqS[bl * 33 + s] = a2 * iw[s] + ib[s];
    }
    __syncthreads();

    // ---- sensory synapse sums (16 samples x 19 neurons = 304 items) ----
    if (t < 304) {
        int n = t % 19, bl = t / 19;
        float wn = 0.f, wd = 0.f;
        #pragma unroll
        for (int s = 0; s < 32; s++) {
            float xx = sc0[s * 19 + n] - sc1[s * 19 + n] * seqS[bl * 33 + s];
            float ee = __builtin_amdgcn_exp2f(xx);
            float uu = __builtin_amdgcn_rcpf(1.f + ee);
            wn = fmaf(swe[s * 19 + n], uu, wn);
            wd = fmaf(swp[s * 19 + n], uu, wd);
        }
        wn_s[(b0 + bl) * 19 + n] = wn;
        wd_s[(b0 + bl) * 19 + n] = wd;
    }
}

// ---------------------------------------------------------------------------
// K3P v3: chunk-parallel LTC scan, one wave per chunk — UNCHANGED (will
// surface in top-5 counters once k12 drops below it).
// ---------------------------------------------------------------------------
__global__ __launch_bounds__(64, 1) void k3p2_scan(
    const float* __restrict__ wn_s, const float* __restrict__ wd_s,
    const float* __restrict__ rc1, const float* __restrict__ rc0,
    const float* __restrict__ rwe, const float* __restrict__ rwp,
    const float* __restrict__ neu,
    const float* __restrict__ out_w, const float* __restrict__ out_b,
    float* __restrict__ out)
{
    const int l    = threadIdx.x;       // 0..63
    const int col  = l & 31;            // target neuron (19 real + 13 pad)
    const int p    = l >> 5;            // source half
    const int cidx = (col < 19) ? col : 0;

    float ca[10], cb[10], cwe[10], cwp[10];
    int gidx[10];
    #pragma unroll
    for (int j = 0; j < 10; j++) {
        int s = p * 10 + j;
        bool e = (col < 19) && (s < 19);
        int idx = e ? (s * 19 + col) : 0;
        ca[j]  = e ? rc1[idx] : 0.f;
        cb[j]  = e ? rc0[idx] : 0.f;
        cwe[j] = e ? rwe[idx] : 0.f;
        cwp[j] = e ? rwp[idx] : 0.f;
        gidx[j] = ((s < 19) ? s : 0) * 4;
    }

    const float cmt  = neu[cidx];
    const float gvl  = neu[64 + cidx];
    const float den0 = neu[128 + cidx];
    const float owv  = out_w[0];
    const float obv  = out_b[0];

    const int c       = blockIdx.x;
    const int s_out   = c * S_PER;
    const int s_begin = (s_out > WARM) ? (s_out - WARM) : 0;
    const int s_end   = s_out + S_PER;
    const int pidx    = (l ^ 32) * 4;

    float v = 0.f;
    float wnc = wn_s[s_begin * 19 + cidx];
    float wdc = wd_s[s_begin * 19 + cidx];

    for (int tt = s_begin; tt < s_end; tt++) {
        int nt = (tt + 1 < T_STEPS) ? (tt + 1) : (T_STEPS - 1);
        float wnn = wn_s[nt * 19 + cidx];
        float wdn = wd_s[nt * 19 + cidx];

        #pragma unroll
        for (int u = 0; u < 6; u++) {
            float pn = 0.f, pd = 0.f;
            #pragma unroll
            for (int j = 0; j < 10; j++) {
                float vs = __int_as_float(
                    __builtin_amdgcn_ds_bpermute(gidx[j], __float_as_int(v)));
                float xx = cb[j] - ca[j] * vs;
                float ee = __builtin_amdgcn_exp2f(xx);
                float uu = __builtin_amdgcn_rcpf(1.f + ee);
                pn = fmaf(cwe[j], uu, pn);
                pd = fmaf(cwp[j], uu, pd);
            }
            pn += __int_as_float(__builtin_amdgcn_ds_bpermute(pidx, __float_as_int(pn)));
            pd += __int_as_float(__builtin_amdgcn_ds_bpermute(pidx, __float_as_int(pd)));
            float num = fmaf(cmt, v, gvl) + (pn + wnc);
            float den = den0 + pd + wdc;
            v = num * __builtin_amdgcn_rcpf(den);
        }
        if (l == 0 && tt >= s_out) out[tt] = fmaf(v, owv, obv);
        wnc = wnn; wdc = wdn;
    }
}

// ---------------------------------------------------------------------------
extern "C" void kernel_launch(void* const* d_in, const int* in_sizes, int n_in,
                              void* d_out, int out_size, void* d_ws, size_t ws_size,
                              hipStream_t stream) {
    const float* x      = (const float*)d_in[0];
    const float* conv_w = (const float*)d_in[1];
    const float* conv_b = (const float*)d_in[2];
    const float* fc1_w  = (const float*)d_in[3];
    const float* fc1_b  = (const float*)d_in[4];
    const float* fc2_w  = (const float*)d_in[5];
    const float* fc2_b  = (const float*)d_in[6];
    const float* iw     = (const float*)d_in[7];
    const float* ib     = (const float*)d_in[8];
    const float* sw     = (const float*)d_in[9];
    const float* smu    = (const float*)d_in[10];
    const float* ssig   = (const float*)d_in[11];
    const float* serev  = (const float*)d_in[12];
    const float* smask  = (const float*)d_in[13];
    const float* w      = (const float*)d_in[14];
    const float* mu     = (const float*)d_in[15];
    const float* sigma  = (const float*)d_in[16];
    const float* erev   = (const float*)d_in[17];
    const float* mask   = (const float*)d_in[18];
    const float* gleak  = (const float*)d_in[19];
    const float* vleak  = (const float*)d_in[20];
    const float* cm     = (const float*)d_in[21];
    const float* ow     = (const float*)d_in[22];
    const float* ob     = (const float*)d_in[23];

    float* ws   = (float*)d_ws;
    float* wn_s = ws;                    // 8192*19 = 155648
    float* wd_s = wn_s + 155648;         // 155648
    float* sc1  = wd_s + 155648;         // 640 each
    float* sc0  = sc1 + 640;
    float* swe  = sc0 + 640;
    float* swp  = swe + 640;
    float* rc1  = swp + 640;             // 384 each
    float* rc0  = rc1 + 384;
    float* rwe  = rc0 + 384;
    float* rwp  = rwe + 384;
    float* neu  = rwp + 384;             // 192  (base ends at 315,584 floats)
    const int use_bsp = (ws_size >= (size_t)WS_NEED_BSP) ? 1 : 0;
    unsigned short* bhi = (unsigned short*)(ws + WS_BASE_FLOATS);
    unsigned short* blo = bhi + 64 * KP;
    (void)in_sizes; (void)n_in; (void)out_size;

    hipLaunchKernelGGL(k0_precompute, dim3(1), dim3(640), 0, stream,
        sw, smu, ssig, serev, smask, w, mu, sigma, erev, mask,
        gleak, vleak, cm, sc1, sc0, swe, swp, rc1, rc0, rwe, rwp, neu);

    if (use_bsp) {
        hipLaunchKernelGGL(k0b_splitB, dim3(64 * KP / 256), dim3(256), 0, stream,
            fc1_w, bhi, blo);
    }

    hipLaunchKernelGGL(k12_frontend, dim3(512), dim3(512), 0, stream,
        x, conv_w, conv_b, fc1_w, fc1_b, fc2_w, fc2_b, iw, ib,
        sc1, sc0, swe, swp, bhi, blo, use_bsp, wn_s, wd_s);

    hipLaunchKernelGGL(k3p2_scan, dim3(SCAN_CHUNKS), dim3(64), 0, stream,
        wn_s, wd_s, rc1, rc0, rwe, rwp, neu, ow, ob, (float*)d_out);
}

// Round 2
// 254.535 us; speedup vs baseline: 1.4502x; 1.0934x over previous
//
#include <hip/hip_runtime.h>
#include <hip/hip_bf16.h>
#include <math.h>

#define L2E 1.4426950408889634f
#define T_STEPS 8192
#define KTOT 5104   // 8 channels * 638 spatial (22*29)
#define EPS_LTC 1e-8f
#define KP 5120     // permuted/padded K (160 chunks x 32)

// scan chunking: 1024 chunks x 8 steps, 16-step burn-in (chunks 0,1 exact).
#define SCAN_CHUNKS 1024
#define S_PER  8
#define WARM   16

// ws layout (floats): base 315,584 f = 1,262,336 B; optional pre-split B adds
// 2 x 327,680 ushorts = 1,310,720 B  ->  total 2,573,056 B (gated on ws_size).
#define WS_BASE_FLOATS 315584
#define WS_NEED_BSP    2573056

typedef __attribute__((ext_vector_type(8))) short bfrag;   // 8 bf16 (4 VGPR)
typedef __attribute__((ext_vector_type(4))) float ffrag;   // 4 fp32 acc
typedef __attribute__((ext_vector_type(4))) float fvec4;

__device__ __forceinline__ float softplus_f(float x) {
    return log1pf(expf(-fabsf(x))) + fmaxf(x, 0.f);
}

__device__ __forceinline__ unsigned short bf_hi(float f) {  // RNE fp32->bf16
    unsigned u = __float_as_uint(f);
    u = u + 0x7FFFu + ((u >> 16) & 1u);
    return (unsigned short)(u >> 16);
}

__device__ __forceinline__ float elu_f(float x) {
    return (x > 0.f) ? x : (__builtin_amdgcn_exp2f(x * L2E) - 1.f);
}

// cross-half (lane i <-> lane i+32) sum without LDS: v_permlane32_swap is a
// VALU op (~8 cy) vs ds_bpermute (~120 cy exposed at 1 wave/SIMD).
__device__ __forceinline__ float half_sum(float x) {
#if __has_builtin(__builtin_amdgcn_permlane32_swap)
    auto r = __builtin_amdgcn_permlane32_swap(__float_as_int(x), __float_as_int(x),
                                              false, false);
    return __int_as_float(r[0]) + __int_as_float(r[1]);
#else
    int pidx = ((threadIdx.x & 63) ^ 32) * 4;
    return x + __int_as_float(
        __builtin_amdgcn_ds_bpermute(pidx, __float_as_int(x)));
#endif
}

// ---------------------------------------------------------------------------
// K0: parameter precompute (tiny).
// ---------------------------------------------------------------------------
__global__ void k0_precompute(
    const float* __restrict__ sw, const float* __restrict__ smu,
    const float* __restrict__ ssig, const float* __restrict__ serev,
    const float* __restrict__ smask,
    const float* __restrict__ w, const float* __restrict__ mu,
    const float* __restrict__ sigma, const float* __restrict__ erev,
    const float* __restrict__ mask,
    const float* __restrict__ gleak, const float* __restrict__ vleak,
    const float* __restrict__ cm,
    float* __restrict__ sc1, float* __restrict__ sc0,
    float* __restrict__ swe, float* __restrict__ swp,
    float* __restrict__ rc1, float* __restrict__ rc0,
    float* __restrict__ rwe, float* __restrict__ rwp,
    float* __restrict__ neu)
{
    int t = threadIdx.x;
    if (t < 608) {   // sensory (32 x 19)
        float sp = softplus_f(sw[t]);
        float c1 = ssig[t] * L2E;
        sc1[t] = c1;
        sc0[t] = c1 * smu[t];
        swe[t] = sp * serev[t];
        swp[t] = sp * smask[t];
    }
    if (t < 361) {   // recurrent (19 x 19), layout [src*19 + tgt]
        float wp = softplus_f(w[t]) * mask[t];
        float c1 = sigma[t] * L2E;
        rc1[t] = c1;
        rc0[t] = c1 * mu[t];
        rwe[t] = wp * erev[t];
        rwp[t] = wp;
    }
    if (t < 64) {
        if (t < 19) {
            float g   = softplus_f(gleak[t]);
            float cmt = softplus_f(cm[t]) * 6.f;   // ODE_UNFOLDS
            neu[t]       = cmt;
            neu[64 + t]  = g * vleak[t];
            neu[128 + t] = cmt + g + EPS_LTC;
        } else {
            neu[t] = 0.f; neu[64 + t] = 0.f; neu[128 + t] = 1.f;
        }
    }
}

// ---------------------------------------------------------------------------
// K0B v2: pre-split fc1_w into bf16 hi/lo, FRAGMENT-INTERLEAVED:
// g = (((kc*16 + q*4 + nt)*16) + mn)*8 + j ; n = nt*16+mn ; o = 2q + (j>>2) ;
// r = kc*4 + (j&3). A wave's per-(kc) B-read is 8 KB contiguous.
// ---------------------------------------------------------------------------
__global__ __launch_bounds__(256) void k0b_splitB(
    const float* __restrict__ fc1_w,
    unsigned short* __restrict__ bhi, unsigned short* __restrict__ blo)
{
    int g = blockIdx.x * 256 + threadIdx.x;   // 0 .. 64*KP-1
    int j  = g & 7;
    int mn = (g >> 3) & 15;
    int nt = (g >> 7) & 3;
    int q  = (g >> 9) & 3;
    int kc = g >> 11;
    int n  = nt * 16 + mn;
    int o  = 2 * q + (j >> 2);
    int r  = kc * 4 + (j & 3);
    float v = (r < 638) ? fc1_w[n * KTOT + o * 638 + r] : 0.f;
    unsigned short h = bf_hi(v);
    bhi[g] = h;
    blo[g] = bf_hi(v - __uint_as_float((unsigned)h << 16));
}

// ---------------------------------------------------------------------------
// K12 v11: LDS-resident x tile (unchanged from R1 — fell out of top-5;
// will re-attack with counters once it is the #1 dispatch).
// ---------------------------------------------------------------------------
__global__ __launch_bounds__(512, 2) void k12_frontend(
    const float* __restrict__ x, const float* __restrict__ conv_w,
    const float* __restrict__ conv_b,
    const float* __restrict__ fc1_w, const float* __restrict__ fc1_b,
    const float* __restrict__ fc2_w, const float* __restrict__ fc2_b,
    const float* __restrict__ iw, const float* __restrict__ ib,
    const float* __restrict__ sc1, const float* __restrict__ sc0,
    const float* __restrict__ swe, const float* __restrict__ swp,
    const unsigned short* __restrict__ bhi,
    const unsigned short* __restrict__ blo, int use_bsp,
    float* __restrict__ wn_s, float* __restrict__ wd_s)
{
    // x tile: 16 samples x 2070 f = 33120 f = 132,480 B (fits 160 KB LDS).
    // After the K-loop (barrier), the same memory is reused as the epilogue
    // buffers (11,920 f needed <= 33,120 f available).
    __shared__ __align__(16) float smem[33120];
    float* redS = smem;            // [8][16][64] = 8192 f partial-C buffer
    float* hS   = smem + 8192;     // 16 x 68 = 1088 f
    float* w2S  = smem + 9312;     // [s][n] stride 65, 2080 f
    float* seqS = smem + 11392;    // [sample][s] stride 33, 528 f

    const int t    = threadIdx.x;   // 0..511
    const int b0   = blockIdx.x * 16;
    const int lane = t & 63;
    const int wv   = t >> 6;        // wave 0..7 -> K eighth
    const int q    = lane >> 4;     // quad -> channel pair 2q,2q+1
    const int mn   = lane & 15;     // sample (A) / out-within-tile (B)
    const int o0   = 2 * q;

    // ---- stage x tile: 8280 float4, perfectly coalesced linear copy ----
    {
        const float* xg = x + (size_t)b0 * 2070;
        #pragma unroll
        for (int i = 0; i < 16; i++) {
            int idx = i * 512 + t;
            fvec4 v;
            __builtin_memcpy(&v, xg + (size_t)idx * 4, 16);
            __builtin_memcpy(smem + (size_t)idx * 4, &v, 16);
        }
        if (t < 88) {               // tail: 8280 - 8192
            int idx = 8192 + t;
            fvec4 v;
            __builtin_memcpy(&v, xg + (size_t)idx * 4, 16);
            __builtin_memcpy(smem + (size_t)idx * 4, &v, 16);
        }
    }
    __syncthreads();

    // conv weights + bias for this lane's channel pair, in registers
    float cw0[12], cw1[12];
    #pragma unroll
    for (int i = 0; i < 12; i++) {
        cw0[i] = conv_w[o0 * 12 + i];
        cw1[i] = conv_w[o0 * 12 + 12 + i];
    }
    const float cb0 = conv_b[o0], cb1 = conv_b[o0 + 1];
    const float* xls = smem + mn * 2070;   // this lane's sample, in LDS

    ffrag acc[4];
    #pragma unroll
    for (int nt = 0; nt < 4; nt++) acc[nt] = (ffrag){0.f, 0.f, 0.f, 0.f};

    const int kc0 = wv * 20;

    // conv+ELU -> split-bf16 A fragments for chunk kc (x read from LDS)
    auto convA = [&](int kc, bfrag& a_hi, bfrag& a_lo) {
        float y0[4], y1[4];
        int r0  = kc * 4;
        int oh0 = (r0 * 565) >> 14;          // == r0/29 for r0 <= 637
        int ow0 = r0 - oh0 * 29;
        if (ow0 <= 25 && r0 + 3 <= 637) {
            // fast path: all 4 positions in conv row oh0; shared 2x5 window
            float xr[3][2][5];
            #pragma unroll
            for (int cc = 0; cc < 3; cc++) {
                const float* a0 = xls + cc * 690 + oh0 * 30 + ow0;
                fvec4 v0, v1;
                __builtin_memcpy(&v0, a0, 16);
                __builtin_memcpy(&v1, a0 + 30, 16);
                xr[cc][0][0] = v0.x; xr[cc][0][1] = v0.y;
                xr[cc][0][2] = v0.z; xr[cc][0][3] = v0.w;
                xr[cc][0][4] = a0[4];
                xr[cc][1][0] = v1.x; xr[cc][1][1] = v1.y;
                xr[cc][1][2] = v1.z; xr[cc][1][3] = v1.w;
                xr[cc][1][4] = a0[34];
            }
            #pragma unroll
            for (int rr = 0; rr < 4; rr++) {
                float a0v = cb0, a1v = cb1;
                #pragma unroll
                for (int cc = 0; cc < 3; cc++) {
                    float x00 = xr[cc][0][rr], x01 = xr[cc][0][rr + 1];
                    float x10 = xr[cc][1][rr], x11 = xr[cc][1][rr + 1];
                    a0v = fmaf(x00, cw0[cc * 4 + 0], a0v);
                    a0v = fmaf(x01, cw0[cc * 4 + 1], a0v);
                    a0v = fmaf(x10, cw0[cc * 4 + 2], a0v);
                    a0v = fmaf(x11, cw0[cc * 4 + 3], a0v);
                    a1v = fmaf(x00, cw1[cc * 4 + 0], a1v);
                    a1v = fmaf(x01, cw1[cc * 4 + 1], a1v);
                    a1v = fmaf(x10, cw1[cc * 4 + 2], a1v);
                    a1v = fmaf(x11, cw1[cc * 4 + 3], a1v);
                }
                y0[rr] = elu_f(a0v);
                y1[rr] = elu_f(a1v);
            }
        } else {
            // slow path (row-crossing or K tail): per-position LDS loads
            #pragma unroll
            for (int rr = 0; rr < 4; rr++) {
                int r = r0 + rr;
                if (r < 638) {
                    int oh = (r * 565) >> 14;
                    const float* xp = xls + oh * 30 + (r - oh * 29);
                    float a0v = cb0, a1v = cb1;
                    #pragma unroll
                    for (int cc = 0; cc < 3; cc++) {
                        float x00 = xp[cc * 690],      x01 = xp[cc * 690 + 1];
                        float x10 = xp[cc * 690 + 30], x11 = xp[cc * 690 + 31];
                        a0v = fmaf(x00, cw0[cc * 4 + 0], a0v);
                        a0v = fmaf(x01, cw0[cc * 4 + 1], a0v);
                        a0v = fmaf(x10, cw0[cc * 4 + 2], a0v);
                        a0v = fmaf(x11, cw0[cc * 4 + 3], a0v);
                        a1v = fmaf(x00, cw1[cc * 4 + 0], a1v);
                        a1v = fmaf(x01, cw1[cc * 4 + 1], a1v);
                        a1v = fmaf(x10, cw1[cc * 4 + 2], a1v);
                        a1v = fmaf(x11, cw1[cc * 4 + 3], a1v);
                    }
                    y0[rr] = elu_f(a0v);
                    y1[rr] = elu_f(a1v);
                } else { y0[rr] = 0.f; y1[rr] = 0.f; }
            }
        }
        #pragma unroll
        for (int j = 0; j < 4; j++) {
            unsigned short h0 = bf_hi(y0[j]);
            a_hi[j] = (short)h0;
            a_lo[j] = (short)bf_hi(y0[j] - __uint_as_float((unsigned)h0 << 16));
            unsigned short h1 = bf_hi(y1[j]);
            a_hi[4 + j] = (short)h1;
            a_lo[4 + j] = (short)bf_hi(y1[j] - __uint_as_float((unsigned)h1 << 16));
        }
    };

    if (use_bsp) {
        auto loadB = [&](int kc, bfrag* bh, bfrag* bl) {
            #pragma unroll
            for (int nt = 0; nt < 4; nt++) {
                size_t off = ((size_t)(kc * 16 + q * 4 + nt) * 16 + mn) * 8;
                bh[nt] = *(const bfrag*)(bhi + off);
                bl[nt] = *(const bfrag*)(blo + off);
            }
        };
        bfrag b_h[4], b_l[4], nb_h[4], nb_l[4];
        loadB(kc0, b_h, b_l);
        for (int kk = 0; kk < 20; kk++) {
            const int kc = kc0 + kk;
            bfrag a_hi, a_lo;
            convA(kc, a_hi, a_lo);
            if (kk < 19) loadB(kc + 1, nb_h, nb_l);   // prefetch before MFMAs
            #pragma unroll
            for (int nt = 0; nt < 4; nt++) {
                acc[nt] = __builtin_amdgcn_mfma_f32_16x16x32_bf16(a_hi, b_h[nt], acc[nt], 0, 0, 0);
                acc[nt] = __builtin_amdgcn_mfma_f32_16x16x32_bf16(a_hi, b_l[nt], acc[nt], 0, 0, 0);
                acc[nt] = __builtin_amdgcn_mfma_f32_16x16x32_bf16(a_lo, b_h[nt], acc[nt], 0, 0, 0);
            }
            #pragma unroll
            for (int nt = 0; nt < 4; nt++) { b_h[nt] = nb_h[nt]; b_l[nt] = nb_l[nt]; }
        }
    } else {
        // fallback: in-loop fp32 load + split (ws too small for pre-split B)
        for (int kk = 0; kk < 20; kk++) {
            const int kc = kc0 + kk;
            bfrag a_hi, a_lo;
            convA(kc, a_hi, a_lo);
            #pragma unroll
            for (int nt = 0; nt < 4; nt++) {
                int n = nt * 16 + mn;
                bfrag b_h, b_l;
                #pragma unroll
                for (int j = 0; j < 8; j++) {
                    int o = o0 + (j >> 2);
                    int r = kc * 4 + (j & 3);
                    float vv = (r < 638) ? fc1_w[(size_t)n * KTOT + o * 638 + r] : 0.f;
                    unsigned short h = bf_hi(vv);
                    b_h[j] = (short)h;
                    b_l[j] = (short)bf_hi(vv - __uint_as_float((unsigned)h << 16));
                }
                acc[nt] = __builtin_amdgcn_mfma_f32_16x16x32_bf16(a_hi, b_h, acc[nt], 0, 0, 0);
                acc[nt] = __builtin_amdgcn_mfma_f32_16x16x32_bf16(a_hi, b_l, acc[nt], 0, 0, 0);
                acc[nt] = __builtin_amdgcn_mfma_f32_16x16x32_bf16(a_lo, b_h, acc[nt], 0, 0, 0);
            }
        }
    }

    // all waves must be done READING the x tile before we overwrite it with
    // the epilogue buffers (smem aliasing).
    __syncthreads();

    // ---- cross-wave K reduction: 8 partials -> LDS -> sum + bias + ReLU ----
    // C/D layout: col = lane&15 -> n-within-tile, row = q*4 + reg -> m.
    #pragma unroll
    for (int nt = 0; nt < 4; nt++) {
        int n = nt * 16 + mn;
        #pragma unroll
        for (int rg = 0; rg < 4; rg++) {
            int m = q * 4 + rg;
            redS[(wv * 16 + m) * 64 + n] = acc[nt][rg];
        }
    }
    __syncthreads();
    #pragma unroll
    for (int e = 0; e < 2; e++) {
        int flat = e * 512 + t;           // 1024 = 16*64
        int m = flat >> 6, n = flat & 63;
        float s = 0.f;
        #pragma unroll
        for (int p = 0; p < 8; p++) s += redS[(p * 16 + m) * 64 + n];
        hS[m * 68 + n] = fmaxf(s + fc1_b[n], 0.f);
    }
    // ---- stage fc2 weights ----
    #pragma unroll
    for (int e = 0; e < 4; e++) {
        int flat = e * 512 + t;           // 2048 = 32*64
        int s = flat >> 6, n = flat & 63;
        w2S[s * 65 + n] = fc2_w[flat];
    }
    __syncthreads();

    // ---- fc2 + input affine -> seq (16 samples x 32 sensory = 512 items) ----
    {
        int s = t & 31, bl = t >> 5;
        float a2 = fc2_b[s];
        #pragma unroll 8
        for (int n = 0; n < 64; n++)
            a2 = fmaf(hS[bl * 68 + n], w2S[s * 65 + n], a2);
        seqS[bl * 33 + s] = a2 * iw[s] + ib[s];
    }
    __syncthreads();

    // ---- sensory synapse sums (16 samples x 19 neurons = 304 items) ----
    if (t < 304) {
        int n = t % 19, bl = t / 19;
        float wn = 0.f, wd = 0.f;
        #pragma unroll
        for (int s = 0; s < 32; s++) {
            float xx = sc0[s * 19 + n] - sc1[s * 19 + n] * seqS[bl * 33 + s];
            float ee = __builtin_amdgcn_exp2f(xx);
            float uu = __builtin_amdgcn_rcpf(1.f + ee);
            wn = fmaf(swe[s * 19 + n], uu, wn);
            wd = fmaf(swp[s * 19 + n], uu, wd);
        }
        wn_s[(b0 + bl) * 19 + n] = wn;
        wd_s[(b0 + bl) * 19 + n] = wd;
    }
}

// ---------------------------------------------------------------------------
// K3P v4: DS-latency fix.
//  v3 counters: 88 us, VALUBusy 23.6%, occupancy 10% (1 wave/SIMD) ->
//  1465 cy/unfold vs ~300 cy of issue work. Cause: 12 ds_bpermute per unfold
//  each exposing ~120 cy (interleaved issue->use->issue as written).
//  Fixes: (1) batch the 10 gather bpermutes into vs[10], one pipelined wait;
//  (2) cross-half reduce via v_permlane32_swap (VALU, ~8 cy) instead of two
//  ds_bpermute round-trips; (3) tree-sum pn/pd instead of a 10-deep serial
//  fmaf chain (40 cy dep -> ~16 cy).
// ---------------------------------------------------------------------------
__global__ __launch_bounds__(64, 1) void k3p2_scan(
    const float* __restrict__ wn_s, const float* __restrict__ wd_s,
    const float* __restrict__ rc1, const float* __restrict__ rc0,
    const float* __restrict__ rwe, const float* __restrict__ rwp,
    const float* __restrict__ neu,
    const float* __restrict__ out_w, const float* __restrict__ out_b,
    float* __restrict__ out)
{
    const int l    = threadIdx.x;       // 0..63
    const int col  = l & 31;            // target neuron (19 real + 13 pad)
    const int p    = l >> 5;            // source half
    const int cidx = (col < 19) ? col : 0;

    float ca[10], cb[10], cwe[10], cwp[10];
    int gidx[10];
    #pragma unroll
    for (int j = 0; j < 10; j++) {
        int s = p * 10 + j;
        bool e = (col < 19) && (s < 19);
        int idx = e ? (s * 19 + col) : 0;
        ca[j]  = e ? rc1[idx] : 0.f;
        cb[j]  = e ? rc0[idx] : 0.f;
        cwe[j] = e ? rwe[idx] : 0.f;
        cwp[j] = e ? rwp[idx] : 0.f;
        gidx[j] = ((s < 19) ? s : 0) * 4;
    }

    const float cmt  = neu[cidx];
    const float gvl  = neu[64 + cidx];
    const float den0 = neu[128 + cidx];
    const float owv  = out_w[0];
    const float obv  = out_b[0];

    const int c       = blockIdx.x;
    const int s_out   = c * S_PER;
    const int s_begin = (s_out > WARM) ? (s_out - WARM) : 0;
    const int s_end   = s_out + S_PER;

    float v = 0.f;
    float wnc = wn_s[s_begin * 19 + cidx];
    float wdc = wd_s[s_begin * 19 + cidx];

    for (int tt = s_begin; tt < s_end; tt++) {
        int nt = (tt + 1 < T_STEPS) ? (tt + 1) : (T_STEPS - 1);
        float wnn = wn_s[nt * 19 + cidx];
        float wdn = wd_s[nt * 19 + cidx];

        #pragma unroll
        for (int u = 0; u < 6; u++) {
            // ---- batched gather: issue all 10 bpermutes, then compute ----
            float vs[10];
            #pragma unroll
            for (int j = 0; j < 10; j++)
                vs[j] = __int_as_float(
                    __builtin_amdgcn_ds_bpermute(gidx[j], __float_as_int(v)));

            float tn[10], td[10];
            #pragma unroll
            for (int j = 0; j < 10; j++) {
                float xx = fmaf(-ca[j], vs[j], cb[j]);
                float ee = __builtin_amdgcn_exp2f(xx);
                float uu = __builtin_amdgcn_rcpf(1.f + ee);
                tn[j] = cwe[j] * uu;
                td[j] = cwp[j] * uu;
            }
            // tree sums (order change vs serial chain is within tolerance)
            float pn = (((tn[0] + tn[1]) + (tn[2] + tn[3]))
                      + ((tn[4] + tn[5]) + (tn[6] + tn[7])))
                      + (tn[8] + tn[9]);
            float pd = (((td[0] + td[1]) + (td[2] + td[3]))
                      + ((td[4] + td[5]) + (td[6] + td[7])))
                      + (td[8] + td[9]);

            // cross-half reduce, VALU-only
            pn = half_sum(pn);
            pd = half_sum(pd);

            float num = fmaf(cmt, v, gvl) + (pn + wnc);
            float den = den0 + pd + wdc;
            v = num * __builtin_amdgcn_rcpf(den);
        }
        if (l == 0 && tt >= s_out) out[tt] = fmaf(v, owv, obv);
        wnc = wnn; wdc = wdn;
    }
}

// ---------------------------------------------------------------------------
extern "C" void kernel_launch(void* const* d_in, const int* in_sizes, int n_in,
                              void* d_out, int out_size, void* d_ws, size_t ws_size,
                              hipStream_t stream) {
    const float* x      = (const float*)d_in[0];
    const float* conv_w = (const float*)d_in[1];
    const float* conv_b = (const float*)d_in[2];
    const float* fc1_w  = (const float*)d_in[3];
    const float* fc1_b  = (const float*)d_in[4];
    const float* fc2_w  = (const float*)d_in[5];
    const float* fc2_b  = (const float*)d_in[6];
    const float* iw     = (const float*)d_in[7];
    const float* ib     = (const float*)d_in[8];
    const float* sw     = (const float*)d_in[9];
    const float* smu    = (const float*)d_in[10];
    const float* ssig   = (const float*)d_in[11];
    const float* serev  = (const float*)d_in[12];
    const float* smask  = (const float*)d_in[13];
    const float* w      = (const float*)d_in[14];
    const float* mu     = (const float*)d_in[15];
    const float* sigma  = (const float*)d_in[16];
    const float* erev   = (const float*)d_in[17];
    const float* mask   = (const float*)d_in[18];
    const float* gleak  = (const float*)d_in[19];
    const float* vleak  = (const float*)d_in[20];
    const float* cm     = (const float*)d_in[21];
    const float* ow     = (const float*)d_in[22];
    const float* ob     = (const float*)d_in[23];

    float* ws   = (float*)d_ws;
    float* wn_s = ws;                    // 8192*19 = 155648
    float* wd_s = wn_s + 155648;         // 155648
    float* sc1  = wd_s + 155648;         // 640 each
    float* sc0  = sc1 + 640;
    float* swe  = sc0 + 640;
    float* swp  = swe + 640;
    float* rc1  = swp + 640;             // 384 each
    float* rc0  = rc1 + 384;
    float* rwe  = rc0 + 384;
    float* rwp  = rwe + 384;
    float* neu  = rwp + 384;             // 192  (base ends at 315,584 floats)
    const int use_bsp = (ws_size >= (size_t)WS_NEED_BSP) ? 1 : 0;
    unsigned short* bhi = (unsigned short*)(ws + WS_BASE_FLOATS);
    unsigned short* blo = bhi + 64 * KP;
    (void)in_sizes; (void)n_in; (void)out_size;

    hipLaunchKernelGGL(k0_precompute, dim3(1), dim3(640), 0, stream,
        sw, smu, ssig, serev, smask, w, mu, sigma, erev, mask,
        gleak, vleak, cm, sc1, sc0, swe, swp, rc1, rc0, rwe, rwp, neu);

    if (use_bsp) {
        hipLaunchKernelGGL(k0b_splitB, dim3(64 * KP / 256), dim3(256), 0, stream,
            fc1_w, bhi, blo);
    }

    hipLaunchKernelGGL(k12_frontend, dim3(512), dim3(512), 0, stream,
        x, conv_w, conv_b, fc1_w, fc1_b, fc2_w, fc2_b, iw, ib,
        sc1, sc0, swe, swp, bhi, blo, use_bsp, wn_s, wd_s);

    hipLaunchKernelGGL(k3p2_scan, dim3(SCAN_CHUNKS), dim3(64), 0, stream,
        wn_s, wd_s, rc1, rc0, rwe, rwp, neu, ow, ob, (float*)d_out);
}